// Round 1
// baseline (81.283 us; speedup 1.0000x reference)
//
#include <hip/hip_runtime.h>
#include <math.h>

#define NB       16
#define IMG      127
#define INC      64
#define SPN      64
#define PN       4096
#define NTHREADS 512
#define PPT      (PN / NTHREADS)   // 8 patches per thread

// index into upper-triangular symmetric 9x9 storage, requires p<=q
__device__ __forceinline__ constexpr int symidx(int p, int q) {
    return p * 9 - (p * (p - 1)) / 2 + (q - p);
}

__global__ void scann_fused(const float* __restrict__ x,
                            const float* __restrict__ Wq, const float* __restrict__ bq,
                            const float* __restrict__ Wk, const float* __restrict__ bk,
                            const float* __restrict__ Wv, const float* __restrict__ bv,
                            const float* __restrict__ Wo, const float* __restrict__ bo,
                            float* __restrict__ out)
{
    __shared__ float plane[IMG * IMG];          // 64516 B: whole channel plane
    __shared__ float red[54 * 8];               // wave partials (45 Gram + 9 sums) x 8 waves
    __shared__ float Msh[45];                   // Gram matrix (upper tri)
    __shared__ float msh[9];                    // column sums
    __shared__ float Wq_s[81], Wk_s[81], Wv_s[81];
    __shared__ float bq_s[9], bk_s[9], bv_s[9], Wo_s[9];
    __shared__ float en[81];                    // energy
    __shared__ float at[81];                    // attn
    __shared__ float wt[9];                     // attn^T @ Wo
    __shared__ float u_s[9];                    // Wv @ wt
    __shared__ float c_s;                       // bv.wt + bo

    const int bg  = blockIdx.x;                 // b*64 + g
    const int g   = bg & 63;
    const int tid = threadIdx.x;

    const float* __restrict__ xp = x + (size_t)bg * (IMG * IMG);

    // stage tiny weights (disjoint thread ranges)
    if (tid < 81) {
        Wq_s[tid] = Wq[g * 81 + tid];
        Wk_s[tid] = Wk[g * 81 + tid];
        Wv_s[tid] = Wv[g * 81 + tid];
    } else if (tid >= 128 && tid < 137) {
        const int i = tid - 128;
        bq_s[i] = bq[g * 9 + i];
        bk_s[i] = bk[g * 9 + i];
        bv_s[i] = bv[g * 9 + i];
        Wo_s[i] = Wo[g * 9 + i];
    }

    // stage the whole channel plane into LDS (coalesced, HBM read exactly once)
    #pragma unroll 4
    for (int i = tid; i < IMG * IMG; i += NTHREADS)
        plane[i] = xp[i];
    __syncthreads();

    // ---- phase 1: Gram matrix M (45 upper-tri) and column sums m (9) ----
    float Macc[45], macc[9];
    #pragma unroll
    for (int i = 0; i < 45; ++i) Macc[i] = 0.f;
    #pragma unroll
    for (int i = 0; i < 9; ++i)  macc[i] = 0.f;

    #pragma unroll
    for (int k = 0; k < PPT; ++k) {
        const int l   = tid + k * NTHREADS;
        const int oh  = l >> 6, ow = l & 63;
        const int ih0 = oh * 2 - 1, iw0 = ow * 2 - 1;
        float v[9];
        #pragma unroll
        for (int kh = 0; kh < 3; ++kh) {
            const int  ih  = ih0 + kh;
            const bool rok = (unsigned)ih < (unsigned)IMG;
            #pragma unroll
            for (int kw = 0; kw < 3; ++kw) {
                const int  iw = iw0 + kw;
                const bool ok = rok && ((unsigned)iw < (unsigned)IMG);
                v[kh * 3 + kw] = ok ? plane[ih * IMG + iw] : 0.f;
            }
        }
        int idx = 0;
        #pragma unroll
        for (int p = 0; p < 9; ++p) {
            macc[p] += v[p];
            #pragma unroll
            for (int q = p; q < 9; ++q)
                Macc[idx++] += v[p] * v[q];
        }
    }

    // wave (64-lane) shuffle reduce, then cross-wave via LDS
    #pragma unroll
    for (int i = 0; i < 45; ++i) {
        float val = Macc[i];
        #pragma unroll
        for (int off = 32; off > 0; off >>= 1) val += __shfl_down(val, off);
        Macc[i] = val;
    }
    #pragma unroll
    for (int i = 0; i < 9; ++i) {
        float val = macc[i];
        #pragma unroll
        for (int off = 32; off > 0; off >>= 1) val += __shfl_down(val, off);
        macc[i] = val;
    }
    const int lane = tid & 63, wv = tid >> 6;   // 8 waves
    if (lane == 0) {
        #pragma unroll
        for (int i = 0; i < 45; ++i) red[i * 8 + wv] = Macc[i];
        #pragma unroll
        for (int i = 0; i < 9; ++i)  red[(45 + i) * 8 + wv] = macc[i];
    }
    __syncthreads();
    if (tid < 54) {
        float s = 0.f;
        #pragma unroll
        for (int w = 0; w < 8; ++w) s += red[tid * 8 + w];
        if (tid < 45) Msh[tid]      = s;
        else          msh[tid - 45] = s;
    }
    __syncthreads();

    // ---- tiny 9x9 math: energy = Wk^T M Wq + (Wk^T m) bq^T + bk (Wq^T m)^T + L bk bq^T
    if (tid < 81) {
        const int s = tid / 9, t = tid % 9;
        float km = 0.f, qm = 0.f;
        #pragma unroll
        for (int p = 0; p < 9; ++p) km += Wk_s[p * 9 + s] * msh[p];
        #pragma unroll
        for (int q = 0; q < 9; ++q) qm += Wq_s[q * 9 + t] * msh[q];
        float e = (float)PN * bk_s[s] * bq_s[t] + km * bq_s[t] + bk_s[s] * qm;
        #pragma unroll
        for (int p = 0; p < 9; ++p) {
            float acc = 0.f;
            #pragma unroll
            for (int q = 0; q < 9; ++q) {
                const int a_ = p < q ? p : q, b_ = p < q ? q : p;
                acc += Msh[symidx(a_, b_)] * Wq_s[q * 9 + t];
            }
            e += Wk_s[p * 9 + s] * acc;
        }
        en[tid] = e;
    }
    __syncthreads();

    // softmax over t per row s
    if (tid < 9) {
        const int s = tid;
        float mx = en[s * 9];
        #pragma unroll
        for (int t = 1; t < 9; ++t) mx = fmaxf(mx, en[s * 9 + t]);
        float ex[9], sum = 0.f;
        #pragma unroll
        for (int t = 0; t < 9; ++t) { ex[t] = expf(en[s * 9 + t] - mx); sum += ex[t]; }
        const float inv = 1.f / sum;
        #pragma unroll
        for (int t = 0; t < 9; ++t) at[s * 9 + t] = ex[t] * inv;
    }
    __syncthreads();

    if (tid < 9) {                               // wt[t] = sum_s attn[s,t] * Wo[s]
        const int t = tid;
        float w = 0.f;
        #pragma unroll
        for (int s = 0; s < 9; ++s) w += at[s * 9 + t] * Wo_s[s];
        wt[t] = w;
    }
    __syncthreads();

    if (tid < 9) {                               // u[p] = sum_t Wv[p,t] * wt[t]
        const int p = tid;
        float uu = 0.f;
        #pragma unroll
        for (int t = 0; t < 9; ++t) uu += Wv_s[p * 9 + t] * wt[t];
        u_s[p] = uu;
    }
    if (tid == 63) {                             // c = bv.wt + bo (same wave, disjoint lanes)
        float cc = bo[g];
        #pragma unroll
        for (int t = 0; t < 9; ++t) cc += bv_s[t] * wt[t];
        c_s = cc;
    }
    __syncthreads();

    // ---- phase 2: out[l] = t_l . u + c, straight from the LDS plane ----
    float ur[9];
    #pragma unroll
    for (int i = 0; i < 9; ++i) ur[i] = u_s[i];
    const float cc = c_s;
    float* __restrict__ op = out + (size_t)bg * PN;

    #pragma unroll
    for (int k = 0; k < PPT; ++k) {
        const int l   = tid + k * NTHREADS;
        const int oh  = l >> 6, ow = l & 63;
        const int ih0 = oh * 2 - 1, iw0 = ow * 2 - 1;
        float o = cc;
        #pragma unroll
        for (int kh = 0; kh < 3; ++kh) {
            const int  ih  = ih0 + kh;
            const bool rok = (unsigned)ih < (unsigned)IMG;
            #pragma unroll
            for (int kw = 0; kw < 3; ++kw) {
                const int  iw = iw0 + kw;
                const bool ok = rok && ((unsigned)iw < (unsigned)IMG);
                o += (ok ? plane[ih * IMG + iw] : 0.f) * ur[kh * 3 + kw];
            }
        }
        op[l] = o;
    }
}

extern "C" void kernel_launch(void* const* d_in, const int* in_sizes, int n_in,
                              void* d_out, int out_size, void* d_ws, size_t ws_size,
                              hipStream_t stream) {
    (void)in_sizes; (void)n_in; (void)d_ws; (void)ws_size; (void)out_size;
    const float* x  = (const float*)d_in[0];
    const float* Wq = (const float*)d_in[1];
    const float* bq = (const float*)d_in[2];
    const float* Wk = (const float*)d_in[3];
    const float* bk = (const float*)d_in[4];
    const float* Wv = (const float*)d_in[5];
    const float* bv = (const float*)d_in[6];
    const float* Wo = (const float*)d_in[7];
    const float* bo = (const float*)d_in[8];
    float* out = (float*)d_out;

    dim3 grid(NB * INC), block(NTHREADS);
    hipLaunchKernelGGL(scann_fused, grid, block, 0, stream,
                       x, Wq, bq, Wk, bk, Wv, bv, Wo, bo, out);
}

// Round 2
// 39.655 us; speedup vs baseline: 2.0498x; 2.0498x over previous
//
#include <hip/hip_runtime.h>
#include <math.h>

#define NB       16
#define IMG      127
#define INC      64
#define PN       4096
#define NTHREADS 512
#define PPT      8                      // consecutive output rows per thread

#define GLOBAL_AS __attribute__((address_space(1)))
#define LDS_AS    __attribute__((address_space(3)))

// index into upper-triangular symmetric 9x9 storage, requires p<=q
__device__ __forceinline__ constexpr int symidx(int p, int q) {
    return p * 9 - (p * (p - 1)) / 2 + (q - p);
}

// full 64-lane sum via DPP adds (VALU pipe only); result valid in lane 63
__device__ __forceinline__ float wave_reduce_sum(float v) {
#define DPP_ADD(ctrl)                                                          \
    v += __builtin_bit_cast(float, __builtin_amdgcn_update_dpp(                \
             0, __builtin_bit_cast(int, v), (ctrl), 0xf, 0xf, true))
    DPP_ADD(0x111);   // row_shr:1
    DPP_ADD(0x112);   // row_shr:2
    DPP_ADD(0x114);   // row_shr:4
    DPP_ADD(0x118);   // row_shr:8  -> lane15/31/47/63 hold row16 sums
    DPP_ADD(0x142);   // row_bcast:15 -> lane31 = sum(0..31), lane63 = sum(32..63)
    DPP_ADD(0x143);   // row_bcast:31 -> lane63 = sum(0..63)
#undef DPP_ADD
    return v;
}

__global__ void __launch_bounds__(NTHREADS, 4)
scann_fused(const float* __restrict__ x,
            const float* __restrict__ Wq, const float* __restrict__ bq,
            const float* __restrict__ Wk, const float* __restrict__ bk,
            const float* __restrict__ Wv, const float* __restrict__ bv,
            const float* __restrict__ Wo, const float* __restrict__ bo,
            float* __restrict__ out)
{
    __shared__ float plane[IMG * IMG];          // 64516 B: whole channel plane
    __shared__ float red[8 * 54];               // per-wave partials (45 Gram + 9 sums)
    __shared__ float Msh[45];                   // Gram matrix (upper tri)
    __shared__ float msh[9];                    // column sums
    __shared__ float Wq_s[81], Wk_s[81], Wv_s[81];
    __shared__ float bq_s[9], bk_s[9], bv_s[9], Wo_s[9];
    __shared__ float en[81];                    // energy
    __shared__ float at[81];                    // attn
    __shared__ float wt[9];                     // attn^T @ Wo
    __shared__ float u_s[9];                    // Wv @ wt
    __shared__ float c_s;                       // bv.wt + bo

    const int bg  = blockIdx.x;                 // b*64 + g
    const int g   = bg & 63;
    const int tid = threadIdx.x;
    const int ow  = tid & 63;                   // lane = output col
    const int wv  = tid >> 6;                   // wave id 0..7
    const int oh0 = wv * PPT;                   // this thread's first output row

    const float* __restrict__ xp = x + (size_t)bg * (IMG * IMG);

    // async-stage the plane: 31 full wave rounds of 4B global_load_lds + scalar tail
    #pragma unroll
    for (int j = 0; j < 31; ++j) {
        __builtin_amdgcn_global_load_lds(
            (const GLOBAL_AS void*)(xp + j * NTHREADS + tid),
            (LDS_AS void*)(&plane[j * NTHREADS + wv * 64]), 4, 0, 0);
    }
    if (tid < IMG * IMG - 31 * NTHREADS)        // 257 remaining floats
        plane[31 * NTHREADS + tid] = xp[31 * NTHREADS + tid];

    // stage tiny weights (disjoint thread ranges)
    if (tid < 81) {
        Wq_s[tid] = Wq[g * 81 + tid];
        Wk_s[tid] = Wk[g * 81 + tid];
        Wv_s[tid] = Wv[g * 81 + tid];
    } else if (tid >= 128 && tid < 137) {
        const int i = tid - 128;
        bq_s[i] = bq[g * 9 + i];
        bk_s[i] = bk[g * 9 + i];
        bv_s[i] = bv[g * 9 + i];
        Wo_s[i] = Wo[g * 9 + i];
    }
    __syncthreads();

    // per-thread constant column validity: iw = 2*ow-1+kw
    const int  iw0 = ow * 2 - 1;
    const bool c0  = (ow > 0), c2 = (ow < 63);

    // ---- phase 1: Gram matrix M (45 upper-tri) and column sums m (9) ----
    float Macc[45], macc[9];
    #pragma unroll
    for (int i = 0; i < 45; ++i) Macc[i] = 0.f;
    #pragma unroll
    for (int i = 0; i < 9; ++i)  macc[i] = 0.f;

    {
        float v[9];
        // rows of first patch (oh0): ih = 2*oh0-1 .. 2*oh0+1
        #pragma unroll
        for (int kh = 0; kh < 3; ++kh) {
            const int  ih  = oh0 * 2 - 1 + kh;
            const bool rok = (unsigned)ih < (unsigned)IMG;
            v[kh * 3 + 0] = (rok && c0) ? plane[ih * IMG + iw0]     : 0.f;
            v[kh * 3 + 1] =  rok        ? plane[ih * IMG + iw0 + 1] : 0.f;
            v[kh * 3 + 2] = (rok && c2) ? plane[ih * IMG + iw0 + 2] : 0.f;
        }
        #pragma unroll
        for (int k = 0; k < PPT; ++k) {
            int idx = 0;
            #pragma unroll
            for (int p = 0; p < 9; ++p) {
                macc[p] += v[p];
                #pragma unroll
                for (int q = p; q < 9; ++q)
                    Macc[idx++] += v[p] * v[q];
            }
            if (k < PPT - 1) {                  // slide down by one patch row (stride 2)
                v[0] = v[6]; v[1] = v[7]; v[2] = v[8];
                #pragma unroll
                for (int kh = 1; kh < 3; ++kh) {
                    const int  ih  = (oh0 + k + 1) * 2 - 1 + kh;
                    const bool rok = (unsigned)ih < (unsigned)IMG;
                    v[kh * 3 + 0] = (rok && c0) ? plane[ih * IMG + iw0]     : 0.f;
                    v[kh * 3 + 1] =  rok        ? plane[ih * IMG + iw0 + 1] : 0.f;
                    v[kh * 3 + 2] = (rok && c2) ? plane[ih * IMG + iw0 + 2] : 0.f;
                }
            }
        }
    }

    // intra-wave reduce on VALU (DPP), lane 63 holds wave sums
    #pragma unroll
    for (int i = 0; i < 45; ++i) Macc[i] = wave_reduce_sum(Macc[i]);
    #pragma unroll
    for (int i = 0; i < 9; ++i)  macc[i] = wave_reduce_sum(macc[i]);
    if (ow == 63) {
        #pragma unroll
        for (int i = 0; i < 45; ++i) red[wv * 54 + i]      = Macc[i];
        #pragma unroll
        for (int i = 0; i < 9; ++i)  red[wv * 54 + 45 + i] = macc[i];
    }
    __syncthreads();
    if (tid < 54) {
        float s = 0.f;
        #pragma unroll
        for (int w = 0; w < 8; ++w) s += red[w * 54 + tid];
        if (tid < 45) Msh[tid]      = s;
        else          msh[tid - 45] = s;
    }
    __syncthreads();

    // ---- tiny 9x9 math: energy = Wk^T M Wq + (Wk^T m) bq^T + bk (Wq^T m)^T + L bk bq^T
    if (tid < 81) {
        const int s = tid / 9, t = tid % 9;
        float km = 0.f, qm = 0.f;
        #pragma unroll
        for (int p = 0; p < 9; ++p) km += Wk_s[p * 9 + s] * msh[p];
        #pragma unroll
        for (int q = 0; q < 9; ++q) qm += Wq_s[q * 9 + t] * msh[q];
        float e = (float)PN * bk_s[s] * bq_s[t] + km * bq_s[t] + bk_s[s] * qm;
        #pragma unroll
        for (int p = 0; p < 9; ++p) {
            float acc = 0.f;
            #pragma unroll
            for (int q = 0; q < 9; ++q) {
                const int a_ = p < q ? p : q, b_ = p < q ? q : p;
                acc += Msh[symidx(a_, b_)] * Wq_s[q * 9 + t];
            }
            e += Wk_s[p * 9 + s] * acc;
        }
        en[tid] = e;
    }
    __syncthreads();

    // softmax over t per row s
    if (tid < 9) {
        const int s = tid;
        float mx = en[s * 9];
        #pragma unroll
        for (int t = 1; t < 9; ++t) mx = fmaxf(mx, en[s * 9 + t]);
        float ex[9], sum = 0.f;
        #pragma unroll
        for (int t = 0; t < 9; ++t) { ex[t] = expf(en[s * 9 + t] - mx); sum += ex[t]; }
        const float inv = 1.f / sum;
        #pragma unroll
        for (int t = 0; t < 9; ++t) at[s * 9 + t] = ex[t] * inv;
    }
    __syncthreads();

    if (tid < 9) {                               // wt[t] = sum_s attn[s,t] * Wo[s]
        const int t = tid;
        float w = 0.f;
        #pragma unroll
        for (int s = 0; s < 9; ++s) w += at[s * 9 + t] * Wo_s[s];
        wt[t] = w;
    }
    __syncthreads();

    if (tid < 9) {                               // u[p] = sum_t Wv[p,t] * wt[t]
        const int p = tid;
        float uu = 0.f;
        #pragma unroll
        for (int t = 0; t < 9; ++t) uu += Wv_s[p * 9 + t] * wt[t];
        u_s[p] = uu;
    }
    if (tid == 63) {                             // c = bv.wt + bo (same wave, disjoint lanes)
        float cc = bo[g];
        #pragma unroll
        for (int t = 0; t < 9; ++t) cc += bv_s[t] * wt[t];
        c_s = cc;
    }
    __syncthreads();

    // ---- phase 2: out[l] = t_l . u + c, same row-sliding traversal ----
    float ur[9];
    #pragma unroll
    for (int i = 0; i < 9; ++i) ur[i] = u_s[i];
    const float cc = c_s;
    float* __restrict__ op = out + (size_t)bg * PN;

    {
        float v[9];
        #pragma unroll
        for (int kh = 0; kh < 3; ++kh) {
            const int  ih  = oh0 * 2 - 1 + kh;
            const bool rok = (unsigned)ih < (unsigned)IMG;
            v[kh * 3 + 0] = (rok && c0) ? plane[ih * IMG + iw0]     : 0.f;
            v[kh * 3 + 1] =  rok        ? plane[ih * IMG + iw0 + 1] : 0.f;
            v[kh * 3 + 2] = (rok && c2) ? plane[ih * IMG + iw0 + 2] : 0.f;
        }
        #pragma unroll
        for (int k = 0; k < PPT; ++k) {
            float o = cc;
            #pragma unroll
            for (int i = 0; i < 9; ++i) o += v[i] * ur[i];
            op[(oh0 + k) * 64 + ow] = o;
            if (k < PPT - 1) {
                v[0] = v[6]; v[1] = v[7]; v[2] = v[8];
                #pragma unroll
                for (int kh = 1; kh < 3; ++kh) {
                    const int  ih  = (oh0 + k + 1) * 2 - 1 + kh;
                    const bool rok = (unsigned)ih < (unsigned)IMG;
                    v[kh * 3 + 0] = (rok && c0) ? plane[ih * IMG + iw0]     : 0.f;
                    v[kh * 3 + 1] =  rok        ? plane[ih * IMG + iw0 + 1] : 0.f;
                    v[kh * 3 + 2] = (rok && c2) ? plane[ih * IMG + iw0 + 2] : 0.f;
                }
            }
        }
    }
}

extern "C" void kernel_launch(void* const* d_in, const int* in_sizes, int n_in,
                              void* d_out, int out_size, void* d_ws, size_t ws_size,
                              hipStream_t stream) {
    (void)in_sizes; (void)n_in; (void)d_ws; (void)ws_size; (void)out_size;
    const float* x  = (const float*)d_in[0];
    const float* Wq = (const float*)d_in[1];
    const float* bq = (const float*)d_in[2];
    const float* Wk = (const float*)d_in[3];
    const float* bk = (const float*)d_in[4];
    const float* Wv = (const float*)d_in[5];
    const float* bv = (const float*)d_in[6];
    const float* Wo = (const float*)d_in[7];
    const float* bo = (const float*)d_in[8];
    float* out = (float*)d_out;

    dim3 grid(NB * INC), block(NTHREADS);
    hipLaunchKernelGGL(scann_fused, grid, block, 0, stream,
                       x, Wq, bq, Wk, bk, Wv, bv, Wo, bo, out);
}